// Round 1
// baseline (6469.928 us; speedup 1.0000x reference)
//
#include <hip/hip_runtime.h>
#include <math.h>

#define NN 325
#define BB 32
#define NB (NN*BB)            // 10400
#define HIDN 64
#define CCOMB 68
#define TENC 6
#define TDEC 12
#define PLANE (NB*CCOMB)      // 707200 floats per plane
#define EPLANES (5*PLANE)     // per-encoder Dbuf stride
#define WSET 65472            // Wzr(43520)+Wc(21760)+bzr(128)+bc(64)

__device__ __constant__ float d_alpha = 0.05f;

static constexpr float ALPHA = 0.05f;
static constexpr float BETA  = 0.95f;
static constexpr float GAMMA = 0.95f;
static constexpr float ISQ2  = 0.7071067811865476f;

// ---------------- workspace offsets (in floats) ----------------
static constexpr size_t OFF_G    = 0;                       // 2*NN*NN = 211250
static constexpr size_t OFF_RS   = OFF_G + 2ull*NN*NN;      // 650
static constexpr size_t OFF_WEFF = OFF_RS + 650;            // 3*WSET = 196416
static constexpr size_t OFF_XS   = OFF_WEFF + 3ull*WSET;    // 2*6*NB*4 = 499200
static constexpr size_t OFF_DBUF = OFF_XS + 2ull*TENC*NB*4; // 2*5*PLANE = 7072000
static constexpr size_t OFF_ZR   = OFF_DBUF + 2ull*EPLANES; // 2*NB*128 = 2662400
static constexpr size_t OFF_HENC = OFF_ZR + 2ull*NB*128;    // 2*NB*64
static constexpr size_t OFF_HDEC = OFF_HENC + 2ull*NB*64;   // NB*64
static constexpr size_t OFF_YS   = OFF_HDEC + (size_t)NB*64;// 12*NB*3
static constexpr size_t WS_TOTAL = OFF_YS + 12ull*NB*3;     // ~13.0M floats = 52 MB

// ---------------- prep kernels ----------------
__global__ void k_sums(const float* __restrict__ adj, float* rs, float* cs) {
    int v = blockIdx.x; int t = threadIdx.x;
    float sr = 0.f, sc = 0.f;
    for (int w = t; w < NN; w += 64) { sr += adj[v*NN + w]; sc += adj[w*NN + v]; }
    for (int o = 32; o > 0; o >>= 1) { sr += __shfl_down(sr, o); sc += __shfl_down(sc, o); }
    if (t == 0) { rs[v] = sr + 1.0f; cs[v] = sc + 1.0f; }
}

__global__ void k_buildG(const float* __restrict__ adj, const float* __restrict__ P,
                         const float* __restrict__ rs, const float* __restrict__ cs,
                         float* __restrict__ G) {
    int idx = blockIdx.x*256 + threadIdx.x;
    if (idx >= NN*NN) return;
    int w = idx / NN, v = idx % NN;
    float d = (v == w) ? 1.0f : 0.0f;
    float a1  = (adj[v*NN + w] + d) / rs[v];
    float a1t = (adj[w*NN + v] + d) / cs[v];
    float p = P[v*NN + w];
    G[idx]         = BETA*a1  + GAMMA*p;   // G_A[w][v]
    G[NN*NN + idx] = BETA*a1t + GAMMA*p;   // G_AT[w][v]
}

// Effective weights: planes [x, h1A, h2A, h1T, h2T] (340 rows).
__global__ void k_weff(const float* __restrict__ W, const float* __restrict__ b,
                       float* __restrict__ Wset) {
    float* Wzr = Wset;            // 340x128
    float* Wc  = Wset + 43520;    // 340x64
    float* bzr = Wset + 65280;    // 128
    float* bc  = Wset + 65408;    // 64
    int tid = blockIdx.x*256 + threadIdx.x;
    if (tid < 340*192) {
        int k = tid / 192, col = tid % 192;
        int g = col >> 6, oo = col & 63;
        const float* Wa = W + (2*g)*204*64;
        const float* Wb = W + (2*g+1)*204*64;
        float val;
        if (k < 68)       val = Wa[k*64+oo] + Wb[k*64+oo];
        else if (k < 204) val = Wa[k*64+oo];
        else              val = Wb[(k-136)*64+oo];
        if (g < 2) Wzr[k*128 + g*64 + oo] = val;
        else       Wc[k*64 + oo] = val;
    }
    if (blockIdx.x == 0 && threadIdx.x < 192) {
        int col = threadIdx.x, g = col >> 6, oo = col & 63;
        float bv = b[(2*g)*64+oo] + b[(2*g+1)*64+oo];
        if (g < 2) bzr[col] = bv; else bc[oo] = bv;
    }
}

// xs[e][t][r][c], r = n*32+b, c<4
__global__ void k_xs(const float* __restrict__ x, const float* __restrict__ st,
                     float* __restrict__ xs) {
    int idx = blockIdx.x*256 + threadIdx.x;
    if (idx >= 2*TENC*NB*4) return;
    int c = idx & 3;
    int r = (idx >> 2) % NB;
    int t = (idx / (4*NB)) % TENC;
    int e = idx / (4*NB*TENC);
    int n = r / BB, b = r % BB;
    float val;
    if (c == 3) {
        float hour   = (st[b*48 + 2*12 + 2*t] + 0.5f) * 23.0f;
        float minute = (st[b*48 + 3*12 + 2*t] + 0.5f) * 59.0f;
        val = floorf((hour*60.0f + minute) / 5.0f);
    } else {
        float xe = x[((b*3 + c)*NN + n)*12 + 2*t];
        float xo = x[((b*3 + c)*NN + n)*12 + 2*t + 1];
        val = (e == 0) ? (xe - xo)*ISQ2 : (xe + xo)*ISQ2;
    }
    xs[idx] = val;
}

__global__ void k_initH(const float* __restrict__ H1_0, const float* __restrict__ H2_0,
                        float* __restrict__ Henc) {
    int idx = blockIdx.x*256 + threadIdx.x;
    if (idx >= 2*NB*64) return;
    int k = idx & 63;
    int r = (idx >> 6) % NB;
    int e = idx / (NB*64);
    int n = r / BB, b = r % BB;
    const float* src = e ? H2_0 : H1_0;
    Henc[idx] = src[((size_t)b*NN + n)*64 + k];
}

// plane0 = [xin(4) | H(64)]
__global__ void k_comb(const float* __restrict__ xs0, const float* __restrict__ xs1,
                       const float* __restrict__ H, float* __restrict__ Dbuf, int E) {
    int idx = blockIdx.x*256 + threadIdx.x;
    if (idx >= E*NB*CCOMB) return;
    int c = idx % CCOMB;
    int r = (idx / CCOMB) % NB;
    int e = idx / (CCOMB*NB);
    const float* xsrc = e ? xs1 : xs0;
    float v = (c < 4) ? xsrc[r*4 + c] : H[((size_t)e*NB + r)*64 + (c-4)];
    Dbuf[(size_t)e*EPLANES + r*CCOMB + c] = v;
}

__global__ void k_comb_dec(const float* __restrict__ prev_y, const float* __restrict__ st,
                           const float* __restrict__ H, float* __restrict__ Dbuf, int t) {
    int idx = blockIdx.x*256 + threadIdx.x;
    if (idx >= NB*CCOMB) return;
    int c = idx % CCOMB;
    int r = idx / CCOMB;
    float v;
    if (c < 3)      v = prev_y ? prev_y[r*3 + c] : 0.0f;
    else if (c == 3){ int b = r % BB; v = floorf((st[b*48 + 2*12 + t] + 0.5f) * 6.0f); }
    else            v = H[r*64 + (c-4)];
    Dbuf[r*CCOMB + c] = v;
}

// overwrite plane0 channels 4:68 with r_gate * H
__global__ void k_comb2(float* __restrict__ Dbuf, const float* __restrict__ ZR,
                        const float* __restrict__ H, int E) {
    int idx = blockIdx.x*256 + threadIdx.x;
    if (idx >= E*NB*64) return;
    int k = idx & 63;
    int r = (idx >> 6) % NB;
    int e = idx / (NB*64);
    float rr = ZR[((size_t)e*NB + r)*128 + 64 + k];
    Dbuf[(size_t)e*EPLANES + r*CCOMB + 4 + k] = rr * H[((size_t)e*NB + r)*64 + k];
}

// ---------------- diffusion GEMM: out = ALPHA*plane0 + G @ plane_in ----------------
// grid (34, 11, 2*E); block 256. Tile 32 rows(n) x 64 cols(j), K-tile 32.
__global__ __launch_bounds__(256) void k_diff(const float* __restrict__ G,
        float* __restrict__ Dbuf, int pinA, int pinT, int poutA, int poutT) {
    int z = blockIdx.z; int e = z >> 1, g = z & 1;
    const float* Gm = G + (size_t)g*NN*NN;
    float* base = Dbuf + (size_t)e*EPLANES;
    int pin  = g ? pinT  : pinA;
    int pout = g ? poutT : poutA;
    const float* X  = base + (size_t)pin*PLANE;
    const float* X0 = base;
    float* Y = base + (size_t)pout*PLANE;
    int n0 = blockIdx.y*32, j0 = blockIdx.x*64;
    int tx = threadIdx.x & 31;     // cols tx, tx+32
    int ty = threadIdx.x >> 5;     // rows ty + 8*i, i<4
    __shared__ float Gt[32][33];
    __shared__ float Xt[32][64];
    float acc[4][2] = {};
    for (int k0 = 0; k0 < NN; k0 += 32) {
        for (int l = threadIdx.x; l < 32*32; l += 256) {
            int i = l >> 5, kk = l & 31;
            int n = n0 + i, v = k0 + kk;
            Gt[i][kk] = (n < NN && v < NN) ? Gm[(size_t)n*NN + v] : 0.0f;
        }
        for (int l = threadIdx.x; l < 32*64; l += 256) {
            int kk = l >> 6, jj = l & 63;
            int v = k0 + kk;
            Xt[kk][jj] = (v < NN) ? X[(size_t)v*2176 + j0 + jj] : 0.0f;
        }
        __syncthreads();
        #pragma unroll 8
        for (int kk = 0; kk < 32; kk++) {
            float xv0 = Xt[kk][tx], xv1 = Xt[kk][tx+32];
            #pragma unroll
            for (int i = 0; i < 4; i++) {
                float gg = Gt[ty + 8*i][kk];
                acc[i][0] = fmaf(gg, xv0, acc[i][0]);
                acc[i][1] = fmaf(gg, xv1, acc[i][1]);
            }
        }
        __syncthreads();
    }
    #pragma unroll
    for (int i = 0; i < 4; i++) {
        int n = n0 + ty + 8*i;
        if (n < NN) {
            size_t off = (size_t)n*2176 + j0 + tx;
            Y[off]      = ALPHA*X0[off]      + acc[i][0];
            Y[off + 32] = ALPHA*X0[off + 32] + acc[i][1];
        }
    }
}

// ---------------- projection GEMM over 5 planes (K=340) ----------------
// mode 0: 128 outputs, sigmoid -> ZR ; mode 1: 64 outputs, tanh -> H update
__global__ __launch_bounds__(256) void k_proj(const float* __restrict__ Dbuf,
        const float* __restrict__ Wbase, int estride,
        float* __restrict__ ZR, float* __restrict__ H, int mode) {
    int e = blockIdx.z;
    const float* base = Dbuf + (size_t)e*EPLANES;
    const float* Wset = Wbase + (size_t)e*estride;
    const float* Wm; const float* bias; int OW;
    if (mode == 0) { Wm = Wset;         bias = Wset + 65280; OW = 128; }
    else           { Wm = Wset + 43520; bias = Wset + 65408; OW = 64; }
    int r0 = blockIdx.y*32, o0 = blockIdx.x*64;
    int tx = threadIdx.x & 31;
    int ty = threadIdx.x >> 5;
    __shared__ float Xt[32][69];
    __shared__ float Wt[68][64];
    float acc[4][2] = {};
    for (int p = 0; p < 5; p++) {
        const float* Xp = base + (size_t)p*PLANE;
        for (int l = threadIdx.x; l < 32*68; l += 256) {
            int i = l / 68, cc = l % 68;
            Xt[i][cc] = Xp[(size_t)(r0 + i)*68 + cc];
        }
        for (int l = threadIdx.x; l < 68*64; l += 256) {
            int kk = l >> 6, oo = l & 63;
            Wt[kk][oo] = Wm[(size_t)(p*68 + kk)*OW + o0 + oo];
        }
        __syncthreads();
        #pragma unroll 4
        for (int kk = 0; kk < 68; kk++) {
            float w0 = Wt[kk][tx], w1 = Wt[kk][tx+32];
            #pragma unroll
            for (int i = 0; i < 4; i++) {
                float xv = Xt[ty + 8*i][kk];
                acc[i][0] = fmaf(xv, w0, acc[i][0]);
                acc[i][1] = fmaf(xv, w1, acc[i][1]);
            }
        }
        __syncthreads();
    }
    #pragma unroll
    for (int i = 0; i < 4; i++) {
        int r = r0 + ty + 8*i;
        #pragma unroll
        for (int jj = 0; jj < 2; jj++) {
            int o = o0 + tx + 32*jj;
            float v = acc[i][jj] + bias[o];
            if (mode == 0) {
                ZR[((size_t)e*NB + r)*128 + o] = 1.0f / (1.0f + expf(-v));
            } else {
                float cval = tanhf(v);
                float zv = ZR[((size_t)e*NB + r)*128 + o];
                size_t hoff = ((size_t)e*NB + r)*64 + o;
                float hv = H[hoff];
                H[hoff] = zv*hv + (1.0f - zv)*cval;
            }
        }
    }
}

// ---------------- fuse + agg (H path only; C path is dead) ----------------
__global__ __launch_bounds__(256) void k_fuse(const float* __restrict__ H1,
        const float* __restrict__ H2,
        const float* __restrict__ wL, const float* __restrict__ bL,
        const float* __restrict__ wH, const float* __restrict__ bH,
        const float* __restrict__ Wcam, const float* __restrict__ bcam,
        const float* __restrict__ Wagg, const float* __restrict__ bagg,
        float* __restrict__ Hdec) {
    int r0 = blockIdx.x*32;
    int tx = threadIdx.x & 31;
    int ty = threadIdx.x >> 5;
    __shared__ float Hm[32][129];
    __shared__ float Hc[32][129];
    for (int l = threadIdx.x; l < 32*64; l += 256) {
        int i = l >> 6, k = l & 63;
        int r = r0 + i, n = r >> 5;
        float h1 = H1[(size_t)r*64 + k], h2 = H2[(size_t)r*64 + k];
        float s = h1 + h2;
        Hm[i][2*k]   = s*wL[n*64+k] + 2.0f*bL[n*64+k];
        Hm[i][2*k+1] = s*wH[n*64+k] + 2.0f*bH[n*64+k];
        Hc[i][k]    = h1;
        Hc[i][64+k] = h2;
    }
    __syncthreads();
    float acc[4][2] = {};
    for (int j = 0; j < 128; j++) {
        float wc0 = 0.3f*Wcam[j*64 + tx],  wc1 = 0.3f*Wcam[j*64 + tx + 32];
        float wa0 = 0.7f*Wagg[j*64 + tx],  wa1 = 0.7f*Wagg[j*64 + tx + 32];
        #pragma unroll
        for (int i = 0; i < 4; i++) {
            float hm = Hm[ty + 8*i][j], hc = Hc[ty + 8*i][j];
            acc[i][0] += hm*wc0 + hc*wa0;
            acc[i][1] += hm*wc1 + hc*wa1;
        }
    }
    #pragma unroll
    for (int i = 0; i < 4; i++) {
        int r = r0 + ty + 8*i;
        Hdec[(size_t)r*64 + tx]      = acc[i][0] + 0.3f*bcam[tx]      + 0.7f*bagg[tx];
        Hdec[(size_t)r*64 + tx + 32] = acc[i][1] + 0.3f*bcam[tx + 32] + 0.7f*bagg[tx + 32];
    }
}

__global__ void k_fc(const float* __restrict__ H, const float* __restrict__ Wfc,
                     const float* __restrict__ bfc, float* __restrict__ y) {
    int idx = blockIdx.x*256 + threadIdx.x;
    if (idx >= NB*3) return;
    int o = idx % 3, r = idx / 3;
    float a = bfc[o];
    #pragma unroll 8
    for (int k = 0; k < 64; k++) a = fmaf(H[(size_t)r*64 + k], Wfc[k*3 + o], a);
    y[idx] = a;
}

__global__ void k_out(const float* __restrict__ ys, float* __restrict__ out) {
    int idx = blockIdx.x*256 + threadIdx.x;
    if (idx >= BB*3*NN*12) return;
    int l = idx % 12;
    int n = (idx / 12) % NN;
    int o = (idx / (12*NN)) % 3;
    int b = idx / (12*NN*3);
    int q = o*12 + l;
    int t = q / 3, c = q % 3;
    out[idx] = ys[((size_t)t*NB + n*BB + b)*3 + c];
}

// ---------------- host ----------------
extern "C" void kernel_launch(void* const* d_in, const int* in_sizes, int n_in,
                              void* d_out, int out_size, void* d_ws, size_t ws_size,
                              hipStream_t stream) {
    const float* x      = (const float*)d_in[0];
    const float* st     = (const float*)d_in[1];
    const float* adj    = (const float*)d_in[2];
    const float* P      = (const float*)d_in[3];
    const float* H1_0   = (const float*)d_in[4];
    const float* H2_0   = (const float*)d_in[6];
    const float* W_encD = (const float*)d_in[8];
    const float* b_encD = (const float*)d_in[9];
    const float* W_encAD= (const float*)d_in[10];
    const float* b_encAD= (const float*)d_in[11];
    const float* W_dec  = (const float*)d_in[12];
    const float* b_dec  = (const float*)d_in[13];
    const float* W_fc   = (const float*)d_in[14];
    const float* b_fc   = (const float*)d_in[15];
    const float* W_aggH = (const float*)d_in[16];
    const float* b_aggH = (const float*)d_in[17];
    const float* W_camH = (const float*)d_in[20];
    const float* b_camH = (const float*)d_in[21];
    const float* wL     = (const float*)d_in[24];
    const float* bL     = (const float*)d_in[25];
    const float* wH     = (const float*)d_in[26];
    const float* bH     = (const float*)d_in[27];

    float* ws   = (float*)d_ws;
    float* G    = ws + OFF_G;
    float* rs   = ws + OFF_RS;
    float* cs   = rs + NN;
    float* Weff = ws + OFF_WEFF;
    float* xs   = ws + OFF_XS;
    float* Dbuf = ws + OFF_DBUF;
    float* ZR   = ws + OFF_ZR;
    float* Henc = ws + OFF_HENC;
    float* Hdec = ws + OFF_HDEC;
    float* ys   = ws + OFF_YS;

    // prep
    k_sums<<<NN, 64, 0, stream>>>(adj, rs, cs);
    k_buildG<<<(NN*NN + 255)/256, 256, 0, stream>>>(adj, P, rs, cs, G);
    k_weff<<<255, 256, 0, stream>>>(W_encD,  b_encD,  Weff);
    k_weff<<<255, 256, 0, stream>>>(W_encAD, b_encAD, Weff + WSET);
    k_weff<<<255, 256, 0, stream>>>(W_dec,   b_dec,   Weff + 2*WSET);
    k_xs<<<(2*TENC*NB*4 + 255)/256, 256, 0, stream>>>(x, st, xs);
    k_initH<<<(2*NB*64 + 255)/256, 256, 0, stream>>>(H1_0, H2_0, Henc);

    // encoders (both streams batched, E=2)
    for (int t = 0; t < TENC; t++) {
        const float* xs0 = xs + (size_t)t*NB*4;
        const float* xs1 = xs + (size_t)(TENC + t)*NB*4;
        k_comb<<<(2*NB*CCOMB + 255)/256, 256, 0, stream>>>(xs0, xs1, Henc, Dbuf, 2);
        k_diff<<<dim3(34,11,4), 256, 0, stream>>>(G, Dbuf, 0,0, 1,3);
        k_diff<<<dim3(34,11,4), 256, 0, stream>>>(G, Dbuf, 1,3, 2,4);
        k_proj<<<dim3(2,325,2), 256, 0, stream>>>(Dbuf, Weff, WSET, ZR, Henc, 0);
        k_comb2<<<(2*NB*64 + 255)/256, 256, 0, stream>>>(Dbuf, ZR, Henc, 2);
        k_diff<<<dim3(34,11,4), 256, 0, stream>>>(G, Dbuf, 0,0, 1,3);
        k_diff<<<dim3(34,11,4), 256, 0, stream>>>(G, Dbuf, 1,3, 2,4);
        k_proj<<<dim3(1,325,2), 256, 0, stream>>>(Dbuf, Weff, WSET, ZR, Henc, 1);
    }

    // fuse + agg (H only)
    k_fuse<<<325, 256, 0, stream>>>(Henc, Henc + (size_t)NB*64,
                                    wL, bL, wH, bH, W_camH, b_camH, W_aggH, b_aggH, Hdec);

    // decoder (E=1)
    for (int t = 0; t < TDEC; t++) {
        const float* prev = (t == 0) ? nullptr : (ys + (size_t)(t-1)*NB*3);
        k_comb_dec<<<(NB*CCOMB + 255)/256, 256, 0, stream>>>(prev, st, Hdec, Dbuf, t);
        k_diff<<<dim3(34,11,2), 256, 0, stream>>>(G, Dbuf, 0,0, 1,3);
        k_diff<<<dim3(34,11,2), 256, 0, stream>>>(G, Dbuf, 1,3, 2,4);
        k_proj<<<dim3(2,325,1), 256, 0, stream>>>(Dbuf, Weff + 2*WSET, 0, ZR, Hdec, 0);
        k_comb2<<<(NB*64 + 255)/256, 256, 0, stream>>>(Dbuf, ZR, Hdec, 1);
        k_diff<<<dim3(34,11,2), 256, 0, stream>>>(G, Dbuf, 0,0, 1,3);
        k_diff<<<dim3(34,11,2), 256, 0, stream>>>(G, Dbuf, 1,3, 2,4);
        k_proj<<<dim3(1,325,1), 256, 0, stream>>>(Dbuf, Weff + 2*WSET, 0, ZR, Hdec, 1);
        k_fc<<<(NB*3 + 255)/256, 256, 0, stream>>>(Hdec, W_fc, b_fc, ys + (size_t)t*NB*3);
    }

    k_out<<<(BB*3*NN*12 + 255)/256, 256, 0, stream>>>(ys, (float*)d_out);
}

// Round 3
// 1647.787 us; speedup vs baseline: 3.9264x; 3.9264x over previous
//
#include <hip/hip_runtime.h>
#include <math.h>

#define NN 325
#define BB 32
#define NB (NN*BB)            // 10400
#define CCOMB 68
#define TENC 6
#define TDEC 12
#define PLANE (NB*CCOMB)      // 707200 floats per plane
#define EPLANES (5*PLANE)
#define WSET 65472            // fp32 Weff: Wzr(340x128)+Wc(340x64)+bzr(128)+bc(64)
#define WT_SET (192*352)      // f16 transposed weights per set
#define M_SET (325*192)       // Mzr[325][128] + Mc[325][64]
#define G16_MAT (384*352)

typedef _Float16 f16;
typedef f16 f16x4 __attribute__((ext_vector_type(4)));
typedef f16 f16x8 __attribute__((ext_vector_type(8)));
typedef float f32x4 __attribute__((ext_vector_type(4)));

static constexpr float ALPHA = 0.05f;
static constexpr float BETA  = 0.95f;
static constexpr float GAMMA = 0.95f;
static constexpr float ISQ2  = 0.7071067811865476f;

// ---------------- workspace offsets (floats) ----------------
static constexpr size_t OFF_G    = 0;                        // 2*NN*NN
static constexpr size_t OFF_RS   = OFF_G + 2ull*NN*NN;       // 650
static constexpr size_t OFF_RV   = OFF_RS + 650;             // 4*325
static constexpr size_t OFF_WEFF = OFF_RV + 1300;            // 3*WSET
static constexpr size_t OFF_WT   = OFF_WEFF + 3ull*WSET;     // 3*WT_SET f16 -> /2 floats
static constexpr size_t OFF_G16  = OFF_WT + (3ull*WT_SET)/2; // 4*G16_MAT f16 -> /2
static constexpr size_t OFF_M    = OFF_G16 + (4ull*G16_MAT)/2;
static constexpr size_t OFF_TV   = OFF_M + 3ull*M_SET;       // 18*32
static constexpr size_t OFF_XS   = OFF_TV + 576;             // 2*6*NB*4
static constexpr size_t OFF_DBUF = OFF_XS + 2ull*TENC*NB*4;  // 2*5*PLANE
static constexpr size_t OFF_ZR   = OFF_DBUF + 2ull*EPLANES;  // 2*NB*128 (G2 aliases here)
static constexpr size_t OFF_HENC = OFF_ZR + 2ull*NB*128;
static constexpr size_t OFF_HDEC = OFF_HENC + 2ull*NB*64;
static constexpr size_t OFF_YS   = OFF_HDEC + (size_t)NB*64;

__device__ inline unsigned pk2(float a, float b) {
    union { f16 h[2]; unsigned u; } x;
    x.h[0] = (f16)a; x.h[1] = (f16)b; return x.u;
}
__device__ inline f16x8 ld8_lds(const f16* p) {   // 8B-aligned LDS read (2x b64)
    f16x4 lo = *(const f16x4*)p;
    f16x4 hi = *(const f16x4*)(p + 4);
    f16x8 r;
    r[0]=lo[0]; r[1]=lo[1]; r[2]=lo[2]; r[3]=lo[3];
    r[4]=hi[0]; r[5]=hi[1]; r[6]=hi[2]; r[7]=hi[3];
    return r;
}

// ---------------- prep ----------------
__global__ void k_sums(const float* __restrict__ adj, float* rs, float* cs) {
    int v = blockIdx.x; int t = threadIdx.x;
    float sr = 0.f, sc = 0.f;
    for (int w = t; w < NN; w += 64) { sr += adj[v*NN + w]; sc += adj[w*NN + v]; }
    for (int o = 32; o > 0; o >>= 1) { sr += __shfl_down(sr, o); sc += __shfl_down(sc, o); }
    if (t == 0) { rs[v] = sr + 1.0f; cs[v] = sc + 1.0f; }
}

__global__ void k_buildG(const float* __restrict__ adj, const float* __restrict__ P,
                         const float* __restrict__ rs, const float* __restrict__ cs,
                         float* __restrict__ G) {
    int idx = blockIdx.x*256 + threadIdx.x;
    if (idx >= NN*NN) return;
    int w = idx / NN, v = idx % NN;
    float d = (v == w) ? 1.0f : 0.0f;
    float a1  = (adj[v*NN + w] + d) / rs[v];
    float a1t = (adj[w*NN + v] + d) / cs[v];
    float p = P[v*NN + w];
    G[idx]         = BETA*a1  + GAMMA*p;   // G_A[n=w][v]
    G[NN*NN + idx] = BETA*a1t + GAMMA*p;   // G_T[n=w][v]
}

// G2 = G @ G (fp32), per direction
__global__ __launch_bounds__(256) void k_gg(const float* __restrict__ G, float* __restrict__ G2) {
    int g = blockIdx.z;
    const float* A = G + (size_t)g*NN*NN;
    float* C = G2 + (size_t)g*NN*NN;
    int n0 = blockIdx.y*32, j0 = blockIdx.x*32;
    int tx = threadIdx.x & 31, ty = threadIdx.x >> 5;
    __shared__ float As[32][33];
    __shared__ float Bs[32][33];
    float acc[4] = {};
    for (int k0 = 0; k0 < NN; k0 += 32) {
        for (int l = threadIdx.x; l < 32*32; l += 256) {
            int i = l >> 5, kk = l & 31;
            int n = n0 + i, k = k0 + kk;
            As[i][kk] = (n < NN && k < NN) ? A[(size_t)n*NN + k] : 0.0f;
            int j = j0 + kk;
            Bs[i][kk] = (k0 + i < NN && j < NN) ? A[(size_t)(k0+i)*NN + j] : 0.0f;
        }
        __syncthreads();
        #pragma unroll 8
        for (int kk = 0; kk < 32; kk++) {
            float bv = Bs[kk][tx];
            #pragma unroll
            for (int i = 0; i < 4; i++) acc[i] = fmaf(As[ty + 8*i][kk], bv, acc[i]);
        }
        __syncthreads();
    }
    #pragma unroll
    for (int i = 0; i < 4; i++) {
        int n = n0 + ty + 8*i, j = j0 + tx;
        if (n < NN && j < NN) C[(size_t)n*NN + j] = acc[i];
    }
}

// G16[m][384][352] f16: m = g*2+s ; s=0: alpha*I+G ; s=1: alpha*I+alpha*G+G2
__global__ void k_g16(const float* __restrict__ G, const float* __restrict__ G2,
                      f16* __restrict__ G16) {
    int idx = blockIdx.x*256 + threadIdx.x;
    if (idx >= 4*G16_MAT) return;
    int m = idx / G16_MAT;
    int rem = idx - m*G16_MAT;
    int n = rem / 352, v = rem - n*352;
    int g = m >> 1, s = m & 1;
    float val = 0.0f;
    if (n < NN && v < NN) {
        float gv = G[(size_t)g*NN*NN + n*NN + v];
        float d = (n == v) ? ALPHA : 0.0f;
        val = (s == 0) ? (gv + d)
                       : (G2[(size_t)g*NN*NN + n*NN + v] + ALPHA*gv + d);
    }
    G16[idx] = (f16)val;
}

// rowsums of G1'/G2' -> rv[4][325] : [r1A, r2A, r1T, r2T]
__global__ void k_rowsum(const float* __restrict__ G, const float* __restrict__ G2,
                         float* __restrict__ rv) {
    int row = blockIdx.x;           // 0..649
    int g = row / NN, n = row - g*NN;
    int t = threadIdx.x;
    float s1 = 0.f, s2 = 0.f;
    for (int v = t; v < NN; v += 64) {
        s1 += G[(size_t)g*NN*NN + n*NN + v];
        s2 += G2[(size_t)g*NN*NN + n*NN + v];
    }
    for (int o = 32; o > 0; o >>= 1) { s1 += __shfl_down(s1, o); s2 += __shfl_down(s2, o); }
    if (t == 0) {
        rv[(g*2 + 0)*NN + n] = ALPHA + s1;
        rv[(g*2 + 1)*NN + n] = ALPHA + ALPHA*s1 + s2;
    }
}

__global__ void k_weff(const float* __restrict__ W, const float* __restrict__ b,
                       float* __restrict__ Wset) {
    float* Wzr = Wset;            // 340x128
    float* Wc  = Wset + 43520;    // 340x64
    float* bzr = Wset + 65280;
    float* bc  = Wset + 65408;
    int tid = blockIdx.x*256 + threadIdx.x;
    if (tid < 340*192) {
        int k = tid / 192, col = tid % 192;
        int g = col >> 6, oo = col & 63;
        const float* Wa = W + (2*g)*204*64;
        const float* Wb = W + (2*g+1)*204*64;
        float val;
        if (k < 68)       val = Wa[k*64+oo] + Wb[k*64+oo];
        else if (k < 204) val = Wa[k*64+oo];
        else              val = Wb[(k-136)*64+oo];
        if (g < 2) Wzr[k*128 + g*64 + oo] = val;
        else       Wc[k*64 + oo] = val;
    }
    if (blockIdx.x == 0 && threadIdx.x < 192) {
        int col = threadIdx.x, g = col >> 6, oo = col & 63;
        float bv = b[(2*g)*64+oo] + b[(2*g+1)*64+oo];
        if (g < 2) bzr[col] = bv; else bc[oo] = bv;
    }
}

// f16 transposed weights: Wt[o][k], o<128 -> zr ; o in 128..191 -> c. t-rows zeroed.
__global__ void k_wt(const float* __restrict__ Weff, f16* __restrict__ Wt) {
    int idx = blockIdx.x*256 + threadIdx.x;
    if (idx >= 192*352) return;
    int o = idx / 352, k = idx - o*352;
    float v = 0.0f;
    if (k < 340) {
        int p = k / 68, c = k - p*68;
        if (c != 3) v = (o < 128) ? Weff[k*128 + o] : Weff[43520 + k*64 + (o - 128)];
    }
    Wt[idx] = (f16)v;
}

// rank-1 t-correction: M[n][o] over zr(128)+c(64)
__global__ void k_M(const float* __restrict__ Weff, const float* __restrict__ rv,
                    float* __restrict__ M) {
    int idx = blockIdx.x*256 + threadIdx.x;
    if (idx >= 325*192) return;
    int n = idx / 192, q = idx - n*192;
    float acc;
    if (q < 128) {
        int o = q;
        acc = Weff[3*128 + o];
        #pragma unroll
        for (int p = 1; p <= 4; p++)
            acc += rv[(p-1)*NN + n] * Weff[(p*68 + 3)*128 + o];
        M[(size_t)n*128 + o] = acc;          // Mzr region [325][128]
    } else {
        int o = q - 128;
        acc = Weff[43520 + 3*64 + o];
        #pragma unroll
        for (int p = 1; p <= 4; p++)
            acc += rv[(p-1)*NN + n] * Weff[43520 + (p*68 + 3)*64 + o];
        M[325*128 + (size_t)n*64 + o] = acc; // Mc region [325][64]
    }
}

// tv[0:6][32] encoder, tv[6:18][32] decoder
__global__ void k_tv(const float* __restrict__ st, float* __restrict__ tv) {
    int idx = blockIdx.x*256 + threadIdx.x;
    if (idx >= 18*32) return;
    int b = idx & 31, t = idx >> 5;
    float v;
    if (t < 6) {
        float hour   = (st[b*48 + 24 + 2*t] + 0.5f) * 23.0f;
        float minute = (st[b*48 + 36 + 2*t] + 0.5f) * 59.0f;
        v = floorf((hour*60.0f + minute) / 5.0f);
    } else {
        int td = t - 6;
        v = floorf((st[b*48 + 24 + td] + 0.5f) * 6.0f);
    }
    tv[idx] = v;
}

__global__ void k_xs(const float* __restrict__ x, const float* __restrict__ st,
                     float* __restrict__ xs) {
    int idx = blockIdx.x*256 + threadIdx.x;
    if (idx >= 2*TENC*NB*4) return;
    int c = idx & 3;
    int r = (idx >> 2) % NB;
    int t = (idx / (4*NB)) % TENC;
    int e = idx / (4*NB*TENC);
    int n = r / BB, b = r % BB;
    float val = 0.0f;
    if (c < 3) {
        float xe = x[((b*3 + c)*NN + n)*12 + 2*t];
        float xo = x[((b*3 + c)*NN + n)*12 + 2*t + 1];
        val = (e == 0) ? (xe - xo)*ISQ2 : (xe + xo)*ISQ2;
    }
    xs[idx] = val;
}

__global__ void k_initH(const float* __restrict__ H1_0, const float* __restrict__ H2_0,
                        float* __restrict__ Henc) {
    int idx = blockIdx.x*256 + threadIdx.x;
    if (idx >= 2*NB*64) return;
    int k = idx & 63;
    int r = (idx >> 6) % NB;
    int e = idx / (NB*64);
    int n = r / BB, b = r % BB;
    const float* src = e ? H2_0 : H1_0;
    Henc[idx] = src[((size_t)b*NN + n)*64 + k];
}

// plane0 = [xin(3) | 0 | H(64)]
__global__ void k_comb(const float* __restrict__ xs0, const float* __restrict__ xs1,
                       const float* __restrict__ H, float* __restrict__ Dbuf, int E) {
    int idx = blockIdx.x*256 + threadIdx.x;
    if (idx >= E*NB*CCOMB) return;
    int c = idx % CCOMB;
    int r = (idx / CCOMB) % NB;
    int e = idx / (CCOMB*NB);
    const float* xsrc = e ? xs1 : xs0;
    float v;
    if (c < 3)       v = xsrc[r*4 + c];
    else if (c == 3) v = 0.0f;
    else             v = H[((size_t)e*NB + r)*64 + (c-4)];
    Dbuf[(size_t)e*EPLANES + r*CCOMB + c] = v;
}

__global__ void k_comb_dec(const float* __restrict__ prev_y,
                           const float* __restrict__ H, float* __restrict__ Dbuf) {
    int idx = blockIdx.x*256 + threadIdx.x;
    if (idx >= NB*CCOMB) return;
    int c = idx % CCOMB;
    int r = idx / CCOMB;
    float v;
    if (c < 3)       v = prev_y ? prev_y[r*3 + c] : 0.0f;
    else if (c == 3) v = 0.0f;
    else             v = H[r*64 + (c-4)];
    Dbuf[r*CCOMB + c] = v;
}

__global__ void k_comb2(float* __restrict__ Dbuf, const float* __restrict__ ZR,
                        const float* __restrict__ H, int E) {
    int idx = blockIdx.x*256 + threadIdx.x;
    if (idx >= E*NB*64) return;
    int k = idx & 63;
    int r = (idx >> 6) % NB;
    int e = idx / (NB*64);
    float rr = ZR[((size_t)e*NB + r)*128 + 64 + k];
    Dbuf[(size_t)e*EPLANES + r*CCOMB + 4 + k] = rr * H[((size_t)e*NB + r)*64 + k];
}

// ---------------- diffusion via MFMA: plane[m+1] = G'[m] @ plane0 ----------------
// grid (34, 6, 4*E), block 256 (4 waves, 2x2), tile 64n x 64j, K=352
__global__ __launch_bounds__(256) void k_diff_mfma(const f16* __restrict__ G16,
        float* __restrict__ Dbuf) {
    int z = blockIdx.z; int e = z >> 2, m = z & 3;
    const f16* Gm = G16 + (size_t)m * G16_MAT;
    const float* X = Dbuf + (size_t)e*EPLANES;               // plane0
    float* Y = Dbuf + (size_t)e*EPLANES + (size_t)(m+1)*PLANE;
    int n0 = blockIdx.y * 64, j0 = blockIdx.x * 64;
    int tid = threadIdx.x;
    int lane = tid & 63, wave = tid >> 6;
    int wm = wave >> 1, wn = wave & 1;
    int l15 = lane & 15, lk = lane >> 4;
    __shared__ f16 Xs[64][36];               // [j_local][v_local(32), pad->36]
    unsigned* Ls = (unsigned*)&Xs[0][0];     // row stride 18 dwords
    int jq = tid & 15, v2 = tid >> 4;        // staging: j-quad, v-pair
    f32x4 acc[2][2] = {};
    for (int k0 = 0; k0 < 352; k0 += 32) {
        int v = k0 + 2*v2;
        float4 f0 = make_float4(0,0,0,0), f1 = make_float4(0,0,0,0);
        if (v < NN)   f0 = *(const float4*)(X + (size_t)v*2176 + j0 + jq*4);
        if (v+1 < NN) f1 = *(const float4*)(X + (size_t)(v+1)*2176 + j0 + jq*4);
        __syncthreads();
        Ls[(jq*4+0)*18 + v2] = pk2(f0.x, f1.x);
        Ls[(jq*4+1)*18 + v2] = pk2(f0.y, f1.y);
        Ls[(jq*4+2)*18 + v2] = pk2(f0.z, f1.z);
        Ls[(jq*4+3)*18 + v2] = pk2(f0.w, f1.w);
        __syncthreads();
        f16x8 afr[2], bfr[2];
        #pragma unroll
        for (int a = 0; a < 2; a++) {
            int n = n0 + wm*32 + a*16 + l15;
            afr[a] = *(const f16x8*)(Gm + (size_t)n*352 + k0 + lk*8);
        }
        #pragma unroll
        for (int b = 0; b < 2; b++) {
            int jl = wn*32 + b*16 + l15;
            bfr[b] = ld8_lds(&Xs[jl][lk*8]);
        }
        #pragma unroll
        for (int a = 0; a < 2; a++)
            #pragma unroll
            for (int b = 0; b < 2; b++)
                acc[a][b] = __builtin_amdgcn_mfma_f32_16x16x32_f16(afr[a], bfr[b], acc[a][b], 0,0,0);
    }
    #pragma unroll
    for (int a = 0; a < 2; a++) {
        #pragma unroll
        for (int b = 0; b < 2; b++) {
            int j = j0 + wn*32 + b*16 + l15;
            #pragma unroll
            for (int r = 0; r < 4; r++) {
                int n = n0 + wm*32 + a*16 + lk*4 + r;
                if (n < NN) Y[(size_t)n*2176 + j] = acc[a][b][r];
            }
        }
    }
}

// ---------------- projection via MFMA over 5 planes, K=340 (pad 352) ----------------
// mode0: OW=128 sigmoid->ZR ; mode1: OW=64 tanh + H update
// grid (OW/64, 163, E), block 256
__global__ __launch_bounds__(256) void k_proj_mfma(const float* __restrict__ Dbuf,
        const f16* __restrict__ WtBase, int wt_stride,
        const float* __restrict__ WeffBase, int weff_stride,
        const float* __restrict__ MBase, int m_stride,
        const float* __restrict__ tv,
        float* __restrict__ ZR, float* __restrict__ H, int mode) {
    int e = blockIdx.z;
    const float* base = Dbuf + (size_t)e*EPLANES;
    const f16* Wt;
    const float* bias;
    const float* M;
    int OW;
    if (mode == 0) {
        Wt = WtBase + (size_t)e*wt_stride;
        bias = WeffBase + (size_t)e*weff_stride + 65280;
        M = MBase + (size_t)e*m_stride;
        OW = 128;
    } else {
        Wt = WtBase + (size_t)e*wt_stride + 128*352;
        bias = WeffBase + (size_t)e*weff_stride + 65408;
        M = MBase + (size_t)e*m_stride + 325*128;
        OW = 64;
    }
    int o0 = blockIdx.x * 64, r0 = blockIdx.y * 64;
    int tid = threadIdx.x;
    int lane = tid & 63, wave = tid >> 6;
    int wm = wave >> 1, wn = wave & 1;
    int l15 = lane & 15, lk = lane >> 4;
    __shared__ f16 As[64][36];
    unsigned* Ls = (unsigned*)&As[0][0];
    int r_l = tid >> 2, kgrp = tid & 3;
    f32x4 acc[2][2] = {};
    for (int k0 = 0; k0 < 352; k0 += 32) {
        int k8 = k0 + kgrp*8;
        float4 fA = make_float4(0,0,0,0), fB = make_float4(0,0,0,0);
        int r = r0 + r_l;
        if (r < NB) {
            if (k8 < 340) {
                int p = k8 / 68, c = k8 - p*68;
                fA = *(const float4*)(base + (size_t)p*PLANE + (size_t)r*68 + c);
            }
            int k8b = k8 + 4;
            if (k8b < 340) {
                int p = k8b / 68, c = k8b - p*68;
                fB = *(const float4*)(base + (size_t)p*PLANE + (size_t)r*68 + c);
            }
        }
        __syncthreads();
        Ls[r_l*18 + kgrp*4 + 0] = pk2(fA.x, fA.y);
        Ls[r_l*18 + kgrp*4 + 1] = pk2(fA.z, fA.w);
        Ls[r_l*18 + kgrp*4 + 2] = pk2(fB.x, fB.y);
        Ls[r_l*18 + kgrp*4 + 3] = pk2(fB.z, fB.w);
        __syncthreads();
        f16x8 afr[2], bfr[2];
        #pragma unroll
        for (int a = 0; a < 2; a++)
            afr[a] = ld8_lds(&As[wm*32 + a*16 + l15][lk*8]);
        #pragma unroll
        for (int b = 0; b < 2; b++) {
            int o = o0 + wn*32 + b*16 + l15;
            bfr[b] = *(const f16x8*)(Wt + (size_t)o*352 + k0 + lk*8);
        }
        #pragma unroll
        for (int a = 0; a < 2; a++)
            #pragma unroll
            for (int b = 0; b < 2; b++)
                acc[a][b] = __builtin_amdgcn_mfma_f32_16x16x32_f16(afr[a], bfr[b], acc[a][b], 0,0,0);
    }
    #pragma unroll
    for (int a = 0; a < 2; a++) {
        #pragma unroll
        for (int b = 0; b < 2; b++) {
            int o = o0 + wn*32 + b*16 + l15;
            #pragma unroll
            for (int rr = 0; rr < 4; rr++) {
                int r = r0 + wm*32 + a*16 + lk*4 + rr;
                if (r >= NB) continue;
                int n = r >> 5, b32 = r & 31;
                float pre = acc[a][b][rr] + bias[o] + tv[b32]*M[(size_t)n*OW + o];
                if (mode == 0) {
                    ZR[((size_t)e*NB + r)*128 + o] = 1.0f / (1.0f + expf(-pre));
                } else {
                    float cval = tanhf(pre);
                    float zv = ZR[((size_t)e*NB + r)*128 + o];
                    size_t hoff = ((size_t)e*NB + r)*64 + o;
                    float hv = H[hoff];
                    H[hoff] = zv*hv + (1.0f - zv)*cval;
                }
            }
        }
    }
}

// ---------------- fuse + agg (H path only) ----------------
__global__ __launch_bounds__(256) void k_fuse(const float* __restrict__ H1,
        const float* __restrict__ H2,
        const float* __restrict__ wL, const float* __restrict__ bL,
        const float* __restrict__ wH, const float* __restrict__ bH,
        const float* __restrict__ Wcam, const float* __restrict__ bcam,
        const float* __restrict__ Wagg, const float* __restrict__ bagg,
        float* __restrict__ Hdec) {
    int r0 = blockIdx.x*32;
    int tx = threadIdx.x & 31;
    int ty = threadIdx.x >> 5;
    __shared__ float Hm[32][129];
    __shared__ float Hc[32][129];
    for (int l = threadIdx.x; l < 32*64; l += 256) {
        int i = l >> 6, k = l & 63;
        int r = r0 + i, n = r >> 5;
        float h1 = H1[(size_t)r*64 + k], h2 = H2[(size_t)r*64 + k];
        float s = h1 + h2;
        Hm[i][2*k]   = s*wL[n*64+k] + 2.0f*bL[n*64+k];
        Hm[i][2*k+1] = s*wH[n*64+k] + 2.0f*bH[n*64+k];
        Hc[i][k]    = h1;
        Hc[i][64+k] = h2;
    }
    __syncthreads();
    float acc[4][2] = {};
    for (int j = 0; j < 128; j++) {
        float wc0 = 0.3f*Wcam[j*64 + tx],  wc1 = 0.3f*Wcam[j*64 + tx + 32];
        float wa0 = 0.7f*Wagg[j*64 + tx],  wa1 = 0.7f*Wagg[j*64 + tx + 32];
        #pragma unroll
        for (int i = 0; i < 4; i++) {
            float hm = Hm[ty + 8*i][j], hc = Hc[ty + 8*i][j];
            acc[i][0] += hm*wc0 + hc*wa0;
            acc[i][1] += hm*wc1 + hc*wa1;
        }
    }
    #pragma unroll
    for (int i = 0; i < 4; i++) {
        int r = r0 + ty + 8*i;
        Hdec[(size_t)r*64 + tx]      = acc[i][0] + 0.3f*bcam[tx]      + 0.7f*bagg[tx];
        Hdec[(size_t)r*64 + tx + 32] = acc[i][1] + 0.3f*bcam[tx + 32] + 0.7f*bagg[tx + 32];
    }
}

__global__ void k_fc(const float* __restrict__ H, const float* __restrict__ Wfc,
                     const float* __restrict__ bfc, float* __restrict__ y) {
    int idx = blockIdx.x*256 + threadIdx.x;
    if (idx >= NB*3) return;
    int o = idx % 3, r = idx / 3;
    float a = bfc[o];
    #pragma unroll 8
    for (int k = 0; k < 64; k++) a = fmaf(H[(size_t)r*64 + k], Wfc[k*3 + o], a);
    y[idx] = a;
}

__global__ void k_out(const float* __restrict__ ys, float* __restrict__ out) {
    int idx = blockIdx.x*256 + threadIdx.x;
    if (idx >= BB*3*NN*12) return;
    int l = idx % 12;
    int n = (idx / 12) % NN;
    int o = (idx / (12*NN)) % 3;
    int b = idx / (12*NN*3);
    int q = o*12 + l;
    int t = q / 3, c = q % 3;
    out[idx] = ys[((size_t)t*NB + n*BB + b)*3 + c];
}

// ---------------- host ----------------
extern "C" void kernel_launch(void* const* d_in, const int* in_sizes, int n_in,
                              void* d_out, int out_size, void* d_ws, size_t ws_size,
                              hipStream_t stream) {
    const float* x      = (const float*)d_in[0];
    const float* st     = (const float*)d_in[1];
    const float* adj    = (const float*)d_in[2];
    const float* P      = (const float*)d_in[3];
    const float* H1_0   = (const float*)d_in[4];
    const float* H2_0   = (const float*)d_in[6];
    const float* W_encD = (const float*)d_in[8];
    const float* b_encD = (const float*)d_in[9];
    const float* W_encAD= (const float*)d_in[10];
    const float* b_encAD= (const float*)d_in[11];
    const float* W_dec  = (const float*)d_in[12];
    const float* b_dec  = (const float*)d_in[13];
    const float* W_fc   = (const float*)d_in[14];
    const float* b_fc   = (const float*)d_in[15];
    const float* W_aggH = (const float*)d_in[16];
    const float* b_aggH = (const float*)d_in[17];
    const float* W_camH = (const float*)d_in[20];
    const float* b_camH = (const float*)d_in[21];
    const float* wL     = (const float*)d_in[24];
    const float* bL     = (const float*)d_in[25];
    const float* wH     = (const float*)d_in[26];
    const float* bH     = (const float*)d_in[27];

    float* ws   = (float*)d_ws;
    float* G    = ws + OFF_G;
    float* rs   = ws + OFF_RS;
    float* cs   = rs + NN;
    float* rv   = ws + OFF_RV;
    float* Weff = ws + OFF_WEFF;
    f16*   Wt   = (f16*)(ws + OFF_WT);
    f16*   G16  = (f16*)(ws + OFF_G16);
    float* Mw   = ws + OFF_M;
    float* tv   = ws + OFF_TV;
    float* xs   = ws + OFF_XS;
    float* Dbuf = ws + OFF_DBUF;
    float* ZR   = ws + OFF_ZR;
    float* G2   = ZR;                 // alias: G2 only used in prep, ZR later
    float* Henc = ws + OFF_HENC;
    float* Hdec = ws + OFF_HDEC;
    float* ys   = ws + OFF_YS;

    // ---- prep ----
    k_sums<<<NN, 64, 0, stream>>>(adj, rs, cs);
    k_buildG<<<(NN*NN + 255)/256, 256, 0, stream>>>(adj, P, rs, cs, G);
    k_gg<<<dim3(11,11,2), 256, 0, stream>>>(G, G2);
    k_g16<<<(4*G16_MAT + 255)/256, 256, 0, stream>>>(G, G2, G16);
    k_rowsum<<<650, 64, 0, stream>>>(G, G2, rv);
    k_weff<<<255, 256, 0, stream>>>(W_encD,  b_encD,  Weff);
    k_weff<<<255, 256, 0, stream>>>(W_encAD, b_encAD, Weff + WSET);
    k_weff<<<255, 256, 0, stream>>>(W_dec,   b_dec,   Weff + 2*WSET);
    k_wt<<<(192*352 + 255)/256, 256, 0, stream>>>(Weff, Wt);
    k_wt<<<(192*352 + 255)/256, 256, 0, stream>>>(Weff + WSET, Wt + WT_SET);
    k_wt<<<(192*352 + 255)/256, 256, 0, stream>>>(Weff + 2*WSET, Wt + 2*WT_SET);
    k_M<<<(325*192 + 255)/256, 256, 0, stream>>>(Weff, rv, Mw);
    k_M<<<(325*192 + 255)/256, 256, 0, stream>>>(Weff + WSET, rv, Mw + M_SET);
    k_M<<<(325*192 + 255)/256, 256, 0, stream>>>(Weff + 2*WSET, rv, Mw + 2*M_SET);
    k_tv<<<3, 256, 0, stream>>>(st, tv);
    k_xs<<<(2*TENC*NB*4 + 255)/256, 256, 0, stream>>>(x, st, xs);
    k_initH<<<(2*NB*64 + 255)/256, 256, 0, stream>>>(H1_0, H2_0, Henc);

    // ---- encoders (E=2) ----
    for (int t = 0; t < TENC; t++) {
        const float* xs0 = xs + (size_t)t*NB*4;
        const float* xs1 = xs + (size_t)(TENC + t)*NB*4;
        const float* tvt = tv + (size_t)t*32;
        k_comb<<<(2*NB*CCOMB + 255)/256, 256, 0, stream>>>(xs0, xs1, Henc, Dbuf, 2);
        k_diff_mfma<<<dim3(34,6,8), 256, 0, stream>>>(G16, Dbuf);
        k_proj_mfma<<<dim3(2,163,2), 256, 0, stream>>>(Dbuf, Wt, WT_SET, Weff, WSET,
                                                       Mw, M_SET, tvt, ZR, Henc, 0);
        k_comb2<<<(2*NB*64 + 255)/256, 256, 0, stream>>>(Dbuf, ZR, Henc, 2);
        k_diff_mfma<<<dim3(34,6,8), 256, 0, stream>>>(G16, Dbuf);
        k_proj_mfma<<<dim3(1,163,2), 256, 0, stream>>>(Dbuf, Wt, WT_SET, Weff, WSET,
                                                       Mw, M_SET, tvt, ZR, Henc, 1);
    }

    k_fuse<<<325, 256, 0, stream>>>(Henc, Henc + (size_t)NB*64,
                                    wL, bL, wH, bH, W_camH, b_camH, W_aggH, b_aggH, Hdec);

    // ---- decoder (E=1, weight set 2) ----
    for (int t = 0; t < TDEC; t++) {
        const float* prev = (t == 0) ? nullptr : (ys + (size_t)(t-1)*NB*3);
        const float* tvt = tv + (size_t)(6 + t)*32;
        k_comb_dec<<<(NB*CCOMB + 255)/256, 256, 0, stream>>>(prev, Hdec, Dbuf);
        k_diff_mfma<<<dim3(34,6,4), 256, 0, stream>>>(G16, Dbuf);
        k_proj_mfma<<<dim3(2,163,1), 256, 0, stream>>>(Dbuf, Wt + 2*WT_SET, 0,
                                                       Weff + 2*WSET, 0,
                                                       Mw + 2*M_SET, 0, tvt, ZR, Hdec, 0);
        k_comb2<<<(NB*64 + 255)/256, 256, 0, stream>>>(Dbuf, ZR, Hdec, 1);
        k_diff_mfma<<<dim3(34,6,4), 256, 0, stream>>>(G16, Dbuf);
        k_proj_mfma<<<dim3(1,163,1), 256, 0, stream>>>(Dbuf, Wt + 2*WT_SET, 0,
                                                       Weff + 2*WSET, 0,
                                                       Mw + 2*M_SET, 0, tvt, ZR, Hdec, 1);
        k_fc<<<(NB*3 + 255)/256, 256, 0, stream>>>(Hdec, W_fc, b_fc, ys + (size_t)t*NB*3);
    }

    k_out<<<(BB*3*NN*12 + 255)/256, 256, 0, stream>>>(ys, (float*)d_out);
}

// Round 4
// 1512.703 us; speedup vs baseline: 4.2771x; 1.0893x over previous
//
#include <hip/hip_runtime.h>
#include <math.h>

#define NN 325
#define BB 32
#define NB (NN*BB)            // 10400
#define CCOMB 68
#define TENC 6
#define TDEC 12
#define PLANE (NB*CCOMB)      // 707200 f16 elements per plane
#define EPLANES (5*PLANE)     // per-encoder Dbuf stride (f16 elems)
#define WSET 65472            // fp32 Weff: Wzr(340x128)+Wc(340x64)+bzr(128)+bc(64)
#define WT_SET (192*352)      // f16 transposed weights per set
#define M_SET (325*192)       // Mzr[325][128] + Mc[325][64]
#define G16_MAT (384*352)

typedef _Float16 f16;
typedef f16 f16x4 __attribute__((ext_vector_type(4)));
typedef f16 f16x8 __attribute__((ext_vector_type(8)));
typedef float f32x4 __attribute__((ext_vector_type(4)));

static constexpr float ALPHA = 0.05f;
static constexpr float BETA  = 0.95f;
static constexpr float GAMMA = 0.95f;
static constexpr float ISQ2  = 0.7071067811865476f;

// ---------------- workspace offsets (floats) ----------------
static constexpr size_t OFF_G    = 0;                        // 2*NN*NN
static constexpr size_t OFF_RS   = OFF_G + 2ull*NN*NN;       // 650
static constexpr size_t OFF_RV   = OFF_RS + 650;             // 1300
static constexpr size_t OFF_WEFF = OFF_RV + 1300;            // 3*WSET
static constexpr size_t OFF_WT   = OFF_WEFF + 3ull*WSET;     // 3*WT_SET f16
static constexpr size_t OFF_G16  = OFF_WT + (3ull*WT_SET)/2; // 4*G16_MAT f16
static constexpr size_t OFF_M    = OFF_G16 + (4ull*G16_MAT)/2;
static constexpr size_t OFF_TV   = OFF_M + 3ull*M_SET;       // 576
static constexpr size_t OFF_XS   = OFF_TV + 576;             // 2*6*NB*4 f16
static constexpr size_t OFF_DBUF = OFF_XS + (2ull*TENC*NB*4)/2;  // 2*EPLANES f16
static constexpr size_t OFF_ZR   = OFF_DBUF + (size_t)EPLANES;   // 2*NB*64 fp32 (G2 aliases)
static constexpr size_t OFF_HENC = OFF_ZR + 2ull*NB*64;
static constexpr size_t OFF_HDEC = OFF_HENC + 2ull*NB*64;
static constexpr size_t OFF_YS   = OFF_HDEC + (size_t)NB*64;

__device__ inline unsigned pk2(float a, float b) {
    union { f16 h[2]; unsigned u; } x;
    x.h[0] = (f16)a; x.h[1] = (f16)b; return x.u;
}
__device__ inline unsigned pk2h(f16 a, f16 b) {
    union { f16 h[2]; unsigned u; } x;
    x.h[0] = a; x.h[1] = b; return x.u;
}
__device__ inline f16x8 ld8_lds(const f16* p) {   // 8B-aligned LDS read (2x b64)
    f16x4 lo = *(const f16x4*)p;
    f16x4 hi = *(const f16x4*)(p + 4);
    f16x8 r;
    r[0]=lo[0]; r[1]=lo[1]; r[2]=lo[2]; r[3]=lo[3];
    r[4]=hi[0]; r[5]=hi[1]; r[6]=hi[2]; r[7]=hi[3];
    return r;
}

// ---------------- prep ----------------
__global__ void k_sums(const float* __restrict__ adj, float* rs, float* cs) {
    int v = blockIdx.x; int t = threadIdx.x;
    float sr = 0.f, sc = 0.f;
    for (int w = t; w < NN; w += 64) { sr += adj[v*NN + w]; sc += adj[w*NN + v]; }
    for (int o = 32; o > 0; o >>= 1) { sr += __shfl_down(sr, o); sc += __shfl_down(sc, o); }
    if (t == 0) { rs[v] = sr + 1.0f; cs[v] = sc + 1.0f; }
}

__global__ void k_buildG(const float* __restrict__ adj, const float* __restrict__ P,
                         const float* __restrict__ rs, const float* __restrict__ cs,
                         float* __restrict__ G) {
    int idx = blockIdx.x*256 + threadIdx.x;
    if (idx >= NN*NN) return;
    int w = idx / NN, v = idx % NN;
    float d = (v == w) ? 1.0f : 0.0f;
    float a1  = (adj[v*NN + w] + d) / rs[v];
    float a1t = (adj[w*NN + v] + d) / cs[v];
    float p = P[v*NN + w];
    G[idx]         = BETA*a1  + GAMMA*p;   // G_A[n=w][v]
    G[NN*NN + idx] = BETA*a1t + GAMMA*p;   // G_T[n=w][v]
}

__global__ __launch_bounds__(256) void k_gg(const float* __restrict__ G, float* __restrict__ G2) {
    int g = blockIdx.z;
    const float* A = G + (size_t)g*NN*NN;
    float* C = G2 + (size_t)g*NN*NN;
    int n0 = blockIdx.y*32, j0 = blockIdx.x*32;
    int tx = threadIdx.x & 31, ty = threadIdx.x >> 5;
    __shared__ float As[32][33];
    __shared__ float Bs[32][33];
    float acc[4] = {};
    for (int k0 = 0; k0 < NN; k0 += 32) {
        for (int l = threadIdx.x; l < 32*32; l += 256) {
            int i = l >> 5, kk = l & 31;
            int n = n0 + i, k = k0 + kk;
            As[i][kk] = (n < NN && k < NN) ? A[(size_t)n*NN + k] : 0.0f;
            int j = j0 + kk;
            Bs[i][kk] = (k0 + i < NN && j < NN) ? A[(size_t)(k0+i)*NN + j] : 0.0f;
        }
        __syncthreads();
        #pragma unroll 8
        for (int kk = 0; kk < 32; kk++) {
            float bv = Bs[kk][tx];
            #pragma unroll
            for (int i = 0; i < 4; i++) acc[i] = fmaf(As[ty + 8*i][kk], bv, acc[i]);
        }
        __syncthreads();
    }
    #pragma unroll
    for (int i = 0; i < 4; i++) {
        int n = n0 + ty + 8*i, j = j0 + tx;
        if (n < NN && j < NN) C[(size_t)n*NN + j] = acc[i];
    }
}

__global__ void k_g16(const float* __restrict__ G, const float* __restrict__ G2,
                      f16* __restrict__ G16) {
    int idx = blockIdx.x*256 + threadIdx.x;
    if (idx >= 4*G16_MAT) return;
    int m = idx / G16_MAT;
    int rem = idx - m*G16_MAT;
    int n = rem / 352, v = rem - n*352;
    int g = m >> 1, s = m & 1;
    float val = 0.0f;
    if (n < NN && v < NN) {
        float gv = G[(size_t)g*NN*NN + n*NN + v];
        float d = (n == v) ? ALPHA : 0.0f;
        val = (s == 0) ? (gv + d)
                       : (G2[(size_t)g*NN*NN + n*NN + v] + ALPHA*gv + d);
    }
    G16[idx] = (f16)val;
}

__global__ void k_rowsum(const float* __restrict__ G, const float* __restrict__ G2,
                         float* __restrict__ rv) {
    int row = blockIdx.x;           // 0..649
    int g = row / NN, n = row - g*NN;
    int t = threadIdx.x;
    float s1 = 0.f, s2 = 0.f;
    for (int v = t; v < NN; v += 64) {
        s1 += G[(size_t)g*NN*NN + n*NN + v];
        s2 += G2[(size_t)g*NN*NN + n*NN + v];
    }
    for (int o = 32; o > 0; o >>= 1) { s1 += __shfl_down(s1, o); s2 += __shfl_down(s2, o); }
    if (t == 0) {
        rv[(g*2 + 0)*NN + n] = ALPHA + s1;
        rv[(g*2 + 1)*NN + n] = ALPHA + ALPHA*s1 + s2;
    }
}

__global__ void k_weff(const float* __restrict__ W, const float* __restrict__ b,
                       float* __restrict__ Wset) {
    float* Wzr = Wset;            // 340x128
    float* Wc  = Wset + 43520;    // 340x64
    float* bzr = Wset + 65280;
    float* bc  = Wset + 65408;
    int tid = blockIdx.x*256 + threadIdx.x;
    if (tid < 340*192) {
        int k = tid / 192, col = tid % 192;
        int g = col >> 6, oo = col & 63;
        const float* Wa = W + (2*g)*204*64;
        const float* Wb = W + (2*g+1)*204*64;
        float val;
        if (k < 68)       val = Wa[k*64+oo] + Wb[k*64+oo];
        else if (k < 204) val = Wa[k*64+oo];
        else              val = Wb[(k-136)*64+oo];
        if (g < 2) Wzr[k*128 + g*64 + oo] = val;
        else       Wc[k*64 + oo] = val;
    }
    if (blockIdx.x == 0 && threadIdx.x < 192) {
        int col = threadIdx.x, g = col >> 6, oo = col & 63;
        float bv = b[(2*g)*64+oo] + b[(2*g+1)*64+oo];
        if (g < 2) bzr[col] = bv; else bc[oo] = bv;
    }
}

__global__ void k_wt(const float* __restrict__ Weff, f16* __restrict__ Wt) {
    int idx = blockIdx.x*256 + threadIdx.x;
    if (idx >= 192*352) return;
    int o = idx / 352, k = idx - o*352;
    float v = 0.0f;
    if (k < 340) {
        int p = k / 68, c = k - p*68;
        if (c != 3) v = (o < 128) ? Weff[k*128 + o] : Weff[43520 + k*64 + (o - 128)];
    }
    Wt[idx] = (f16)v;
}

__global__ void k_M(const float* __restrict__ Weff, const float* __restrict__ rv,
                    float* __restrict__ M) {
    int idx = blockIdx.x*256 + threadIdx.x;
    if (idx >= 325*192) return;
    int n = idx / 192, q = idx - n*192;
    float acc;
    if (q < 128) {
        int o = q;
        acc = Weff[3*128 + o];
        #pragma unroll
        for (int p = 1; p <= 4; p++)
            acc += rv[(p-1)*NN + n] * Weff[(p*68 + 3)*128 + o];
        M[(size_t)n*128 + o] = acc;
    } else {
        int o = q - 128;
        acc = Weff[43520 + 3*64 + o];
        #pragma unroll
        for (int p = 1; p <= 4; p++)
            acc += rv[(p-1)*NN + n] * Weff[43520 + (p*68 + 3)*64 + o];
        M[325*128 + (size_t)n*64 + o] = acc;
    }
}

__global__ void k_tv(const float* __restrict__ st, float* __restrict__ tv) {
    int idx = blockIdx.x*256 + threadIdx.x;
    if (idx >= 18*32) return;
    int b = idx & 31, t = idx >> 5;
    float v;
    if (t < 6) {
        float hour   = (st[b*48 + 24 + 2*t] + 0.5f) * 23.0f;
        float minute = (st[b*48 + 36 + 2*t] + 0.5f) * 59.0f;
        v = floorf((hour*60.0f + minute) / 5.0f);
    } else {
        int td = t - 6;
        v = floorf((st[b*48 + 24 + td] + 0.5f) * 6.0f);
    }
    tv[idx] = v;
}

__global__ void k_xs16(const float* __restrict__ x, f16* __restrict__ xs) {
    int idx = blockIdx.x*256 + threadIdx.x;
    if (idx >= 2*TENC*NB*4) return;
    int c = idx & 3;
    int r = (idx >> 2) % NB;
    int t = (idx / (4*NB)) % TENC;
    int e = idx / (4*NB*TENC);
    int n = r / BB, b = r % BB;
    float val = 0.0f;
    if (c < 3) {
        float xe = x[((b*3 + c)*NN + n)*12 + 2*t];
        float xo = x[((b*3 + c)*NN + n)*12 + 2*t + 1];
        val = (e == 0) ? (xe - xo)*ISQ2 : (xe + xo)*ISQ2;
    }
    xs[idx] = (f16)val;
}

__global__ void k_initH(const float* __restrict__ H1_0, const float* __restrict__ H2_0,
                        float* __restrict__ Henc) {
    int idx = blockIdx.x*256 + threadIdx.x;
    if (idx >= 2*NB*64) return;
    int k = idx & 63;
    int r = (idx >> 6) % NB;
    int e = idx / (NB*64);
    int n = r / BB, b = r % BB;
    const float* src = e ? H2_0 : H1_0;
    Henc[idx] = src[((size_t)b*NN + n)*64 + k];
}

// plane0 init: [x0(3) | 0 | H0(64)] f16 for both encoders
__global__ void k_init0(const f16* __restrict__ xs, const float* __restrict__ H1_0,
                        const float* __restrict__ H2_0, f16* __restrict__ Dbuf16) {
    int idx = blockIdx.x*256 + threadIdx.x;
    if (idx >= 2*NB*CCOMB) return;
    int c = idx % CCOMB;
    int r = (idx / CCOMB) % NB;
    int e = idx / (CCOMB*NB);
    int n = r >> 5, b = r & 31;
    f16 v;
    if (c < 3)       v = xs[((size_t)e*TENC)*NB*4 + (size_t)r*4 + c];
    else if (c == 3) v = (f16)0.0f;
    else {
        const float* h0 = e ? H2_0 : H1_0;
        v = (f16)h0[((size_t)b*NN + n)*64 + (c-4)];
    }
    Dbuf16[(size_t)e*EPLANES + (size_t)r*CCOMB + c] = v;
}

// ---------------- diffusion via MFMA (f16 planes): plane[m+1] = G'[m] @ plane0 ----
// grid (34, 6, 4*E), block 256 (4 waves 2x2), tile 64n x 64j, K=352
__global__ __launch_bounds__(256) void k_diff16(const f16* __restrict__ G16,
        f16* __restrict__ Dbuf16) {
    int z = blockIdx.z; int e = z >> 2, m = z & 3;
    const f16* Gm = G16 + (size_t)m * G16_MAT;
    const f16* X = Dbuf16 + (size_t)e*EPLANES;               // plane0
    f16* Y = Dbuf16 + (size_t)e*EPLANES + (size_t)(m+1)*PLANE;
    int n0 = blockIdx.y * 64, j0 = blockIdx.x * 64;
    int tid = threadIdx.x;
    int lane = tid & 63, wave = tid >> 6;
    int wm = wave >> 1, wn = wave & 1;
    int l15 = lane & 15, lk = lane >> 4;
    __shared__ f16 Xs[64*36];                // [j_local][v-pairs], row stride 36 f16
    unsigned* Ls = (unsigned*)Xs;            // row stride 18 dwords
    int jq = tid & 15, v2 = tid >> 4;
    f32x4 acc[2][2] = {};
    for (int k0 = 0; k0 < 352; k0 += 32) {
        int v = k0 + 2*v2;
        f16x4 h0 = {}, h1 = {};
        if (v < NN)   h0 = *(const f16x4*)(X + (size_t)v*2176 + j0 + jq*4);
        if (v+1 < NN) h1 = *(const f16x4*)(X + (size_t)(v+1)*2176 + j0 + jq*4);
        __syncthreads();
        Ls[(jq*4+0)*18 + v2] = pk2h(h0[0], h1[0]);
        Ls[(jq*4+1)*18 + v2] = pk2h(h0[1], h1[1]);
        Ls[(jq*4+2)*18 + v2] = pk2h(h0[2], h1[2]);
        Ls[(jq*4+3)*18 + v2] = pk2h(h0[3], h1[3]);
        __syncthreads();
        f16x8 afr[2], bfr[2];
        #pragma unroll
        for (int a = 0; a < 2; a++) {
            int n = n0 + wm*32 + a*16 + l15;
            afr[a] = *(const f16x8*)(Gm + (size_t)n*352 + k0 + lk*8);
        }
        #pragma unroll
        for (int b = 0; b < 2; b++) {
            int jl = wn*32 + b*16 + l15;
            bfr[b] = ld8_lds(Xs + jl*36 + lk*8);
        }
        #pragma unroll
        for (int a = 0; a < 2; a++)
            #pragma unroll
            for (int b = 0; b < 2; b++)
                acc[a][b] = __builtin_amdgcn_mfma_f32_16x16x32_f16(afr[a], bfr[b], acc[a][b], 0,0,0);
    }
    #pragma unroll
    for (int a = 0; a < 2; a++) {
        #pragma unroll
        for (int b = 0; b < 2; b++) {
            int j = j0 + wn*32 + b*16 + l15;
            #pragma unroll
            for (int r = 0; r < 4; r++) {
                int n = n0 + wm*32 + a*16 + lk*4 + r;
                if (n < NN) Y[(size_t)n*2176 + j] = (f16)acc[a][b][r];
            }
        }
    }
}

// ---------------- projection via MFMA over 5 f16 planes, K=340 (pad 352) --------
// MODE 0: 128 outputs (z,r): z->ZR fp32, r -> plane0 (r*H) f16.  grid (163,E)
// MODE 1: 64 outputs (C): H update -> Hstate fp32 + plane0 f16 (+ next-x).
template<int MODE>
__global__ __launch_bounds__(256) void k_proj16(f16* __restrict__ Dbuf16,
        const f16* __restrict__ WtBase, int wt_stride,
        const float* __restrict__ WeffBase, int weff_stride,
        const float* __restrict__ MBase, int m_stride,
        const float* __restrict__ tv,
        float* __restrict__ ZR, float* __restrict__ Hstate,
        const f16* __restrict__ xn0, const f16* __restrict__ xn1) {
    constexpr int BF = (MODE == 0) ? 4 : 2;
    constexpr int OW = (MODE == 0) ? 128 : 64;
    int e = blockIdx.y;
    const f16* base = Dbuf16 + (size_t)e*EPLANES;
    f16* Dp0 = Dbuf16 + (size_t)e*EPLANES;   // plane0
    const f16* Wt = WtBase + (size_t)e*wt_stride + (MODE == 1 ? 128*352 : 0);
    const float* bias = WeffBase + (size_t)e*weff_stride + (MODE == 0 ? 65280 : 65408);
    const float* M = MBase + (size_t)e*m_stride + (MODE == 1 ? 325*128 : 0);
    int r0 = blockIdx.x * 64;
    int tid = threadIdx.x;
    int lane = tid & 63, wave = tid >> 6;
    int wm = wave >> 1, wn = wave & 1;
    int l15 = lane & 15, lk = lane >> 4;
    __shared__ f16 As[64*36];
    unsigned* Ls = (unsigned*)As;
    int r_l = tid >> 2, kgrp = tid & 3;
    f32x4 acc[2][BF] = {};
    for (int k0 = 0; k0 < 352; k0 += 32) {
        int k8 = k0 + kgrp*8;
        f16x4 fA = {}, fB = {};
        int r = r0 + r_l;
        if (r < NB) {
            if (k8 < 340) {
                int p = k8 / 68, c = k8 - p*68;
                fA = *(const f16x4*)(base + (size_t)p*PLANE + (size_t)r*68 + c);
            }
            int k8b = k8 + 4;
            if (k8b < 340) {
                int p = k8b / 68, c = k8b - p*68;
                fB = *(const f16x4*)(base + (size_t)p*PLANE + (size_t)r*68 + c);
            }
        }
        __syncthreads();
        union { f16x4 h; unsigned u[2]; } ca, cb;
        ca.h = fA; cb.h = fB;
        Ls[r_l*18 + kgrp*4 + 0] = ca.u[0];
        Ls[r_l*18 + kgrp*4 + 1] = ca.u[1];
        Ls[r_l*18 + kgrp*4 + 2] = cb.u[0];
        Ls[r_l*18 + kgrp*4 + 3] = cb.u[1];
        __syncthreads();
        f16x8 afr[2], bfr[BF];
        #pragma unroll
        for (int a = 0; a < 2; a++)
            afr[a] = ld8_lds(As + (wm*32 + a*16 + l15)*36 + lk*8);
        #pragma unroll
        for (int b = 0; b < BF; b++) {
            int o = (MODE == 0 ? wn*64 : wn*32) + b*16 + l15;
            bfr[b] = *(const f16x8*)(Wt + (size_t)o*352 + k0 + lk*8);
        }
        #pragma unroll
        for (int a = 0; a < 2; a++)
            #pragma unroll
            for (int b = 0; b < BF; b++)
                acc[a][b] = __builtin_amdgcn_mfma_f32_16x16x32_f16(afr[a], bfr[b], acc[a][b], 0,0,0);
    }
    #pragma unroll
    for (int a = 0; a < 2; a++) {
        #pragma unroll
        for (int b = 0; b < BF; b++) {
            int o = (MODE == 0 ? wn*64 : wn*32) + b*16 + l15;
            #pragma unroll
            for (int rr = 0; rr < 4; rr++) {
                int r = r0 + wm*32 + a*16 + lk*4 + rr;
                if (r >= NB) continue;
                int n = r >> 5, b32 = r & 31;
                float pre = acc[a][b][rr] + bias[o] + tv[b32]*M[(size_t)n*OW + o];
                if (MODE == 0) {
                    float sg = 1.0f / (1.0f + expf(-pre));
                    if (o < 64) {
                        ZR[((size_t)e*NB + r)*64 + o] = sg;
                    } else {
                        float hv = Hstate[((size_t)e*NB + r)*64 + (o - 64)];
                        Dp0[(size_t)r*68 + 4 + (o - 64)] = (f16)(sg * hv);
                    }
                } else {
                    float cval = tanhf(pre);
                    float zv = ZR[((size_t)e*NB + r)*64 + o];
                    size_t hoff = ((size_t)e*NB + r)*64 + o;
                    float hv = Hstate[hoff];
                    float hnew = zv*hv + (1.0f - zv)*cval;
                    Hstate[hoff] = hnew;
                    Dp0[(size_t)r*68 + 4 + o] = (f16)hnew;
                    if (o < 3) {
                        const f16* xn = e ? xn1 : xn0;
                        if (xn) Dp0[(size_t)r*68 + o] = xn[(size_t)r*4 + o];
                    }
                }
            }
        }
    }
}

// ---------------- fuse + agg via MFMA: Hdec = [Hm|Hc] @ [0.3Wcam;0.7Wagg] + b ----
// grid (163), block 256. Also initializes decoder plane0 (H channels + zero c0..3).
__global__ __launch_bounds__(256) void k_fuse16(const float* __restrict__ H1,
        const float* __restrict__ H2,
        const float* __restrict__ wL, const float* __restrict__ bL,
        const float* __restrict__ wH, const float* __restrict__ bH,
        const float* __restrict__ Wcam, const float* __restrict__ bcam,
        const float* __restrict__ Wagg, const float* __restrict__ bagg,
        float* __restrict__ Hdec, f16* __restrict__ Dp0) {
    int r0 = blockIdx.x * 64;
    int tid = threadIdx.x;
    int lane = tid & 63, wave = tid >> 6;
    int wm = wave >> 1, wn = wave & 1;
    int l15 = lane & 15, lk = lane >> 4;
    __shared__ f16 Al[64*264];       // rows r, k 0..255, stride 264 f16 (132 dw)
    __shared__ f16 Wl[64*264];       // rows o, k 0..255
    unsigned* La = (unsigned*)Al;
    unsigned* Lw = (unsigned*)Wl;
    // A: Hm part (k 0..127 -> dwords 0..63)
    for (int l = tid; l < 64*64; l += 256) {
        int i = l >> 6, k = l & 63;
        int r = r0 + i;
        unsigned val = 0;
        if (r < NB) {
            int n = r >> 5;
            float h1 = H1[(size_t)r*64 + k], h2 = H2[(size_t)r*64 + k];
            float s = h1 + h2;
            val = pk2(s*wL[n*64+k] + 2.0f*bL[n*64+k], s*wH[n*64+k] + 2.0f*bH[n*64+k]);
        }
        La[i*132 + k] = val;
    }
    // A: Hc = [H1 | H2]  (k 128..191 = H1, 192..255 = H2)
    for (int l = tid; l < 64*32; l += 256) {
        int i = l >> 5, kp = l & 31;
        int r = r0 + i;
        unsigned v1 = 0, v2 = 0;
        if (r < NB) {
            float2 a = *(const float2*)(H1 + (size_t)r*64 + 2*kp);
            float2 b = *(const float2*)(H2 + (size_t)r*64 + 2*kp);
            v1 = pk2(a.x, a.y);
            v2 = pk2(b.x, b.y);
        }
        La[i*132 + 64 + kp] = v1;
        La[i*132 + 96 + kp] = v2;
    }
    // W: rows o, k-pairs kp 0..63 from 0.3*Wcam, 64..127 from 0.7*Wagg
    for (int idx = tid; idx < 64*128; idx += 256) {
        int kp = idx & 63, half = (idx >> 6) & 1, o = idx >> 7;
        // iterate o 0..63 with kp fast: idx = o*128 + half*64 + kp
        float a, b;
        if (half == 0) {
            a = 0.3f * Wcam[(size_t)(2*kp)*64 + o];
            b = 0.3f * Wcam[(size_t)(2*kp+1)*64 + o];
            Lw[o*132 + kp] = pk2(a, b);
        } else {
            a = 0.7f * Wagg[(size_t)(2*kp)*64 + o];
            b = 0.7f * Wagg[(size_t)(2*kp+1)*64 + o];
            Lw[o*132 + 64 + kp] = pk2(a, b);
        }
    }
    __syncthreads();
    f32x4 acc[2][2] = {};
    for (int k0 = 0; k0 < 256; k0 += 32) {
        f16x8 afr[2], bfr[2];
        #pragma unroll
        for (int a = 0; a < 2; a++)
            afr[a] = ld8_lds(Al + (wm*32 + a*16 + l15)*264 + k0 + lk*8);
        #pragma unroll
        for (int b = 0; b < 2; b++)
            bfr[b] = ld8_lds(Wl + (wn*32 + b*16 + l15)*264 + k0 + lk*8);
        #pragma unroll
        for (int a = 0; a < 2; a++)
            #pragma unroll
            for (int b = 0; b < 2; b++)
                acc[a][b] = __builtin_amdgcn_mfma_f32_16x16x32_f16(afr[a], bfr[b], acc[a][b], 0,0,0);
    }
    #pragma unroll
    for (int a = 0; a < 2; a++) {
        #pragma unroll
        for (int b = 0; b < 2; b++) {
            int o = wn*32 + b*16 + l15;
            float bo = 0.3f*bcam[o] + 0.7f*bagg[o];
            #pragma unroll
            for (int rr = 0; rr < 4; rr++) {
                int r = r0 + wm*32 + a*16 + lk*4 + rr;
                if (r >= NB) continue;
                float val = acc[a][b][rr] + bo;
                Hdec[(size_t)r*64 + o] = val;
                Dp0[(size_t)r*68 + 4 + o] = (f16)val;
            }
        }
    }
    // zero decoder x/t channels c0..3
    {
        int l = tid;
        if (l < 256) {
            int r = r0 + (l >> 2);
            if (r < NB) Dp0[(size_t)r*68 + (l & 3)] = (f16)0.0f;
        }
    }
}

__global__ void k_fc(const float* __restrict__ H, const float* __restrict__ Wfc,
                     const float* __restrict__ bfc, float* __restrict__ y,
                     f16* __restrict__ Dp0) {
    int idx = blockIdx.x*256 + threadIdx.x;
    if (idx >= NB*3) return;
    int o = idx % 3, r = idx / 3;
    float a = bfc[o];
    #pragma unroll 8
    for (int k = 0; k < 64; k++) a = fmaf(H[(size_t)r*64 + k], Wfc[k*3 + o], a);
    y[idx] = a;
    Dp0[(size_t)r*68 + o] = (f16)a;   // next decoder step's x
}

__global__ void k_out(const float* __restrict__ ys, float* __restrict__ out) {
    int idx = blockIdx.x*256 + threadIdx.x;
    if (idx >= BB*3*NN*12) return;
    int l = idx % 12;
    int n = (idx / 12) % NN;
    int o = (idx / (12*NN)) % 3;
    int b = idx / (12*NN*3);
    int q = o*12 + l;
    int t = q / 3, c = q % 3;
    out[idx] = ys[((size_t)t*NB + n*BB + b)*3 + c];
}

// ---------------- host ----------------
extern "C" void kernel_launch(void* const* d_in, const int* in_sizes, int n_in,
                              void* d_out, int out_size, void* d_ws, size_t ws_size,
                              hipStream_t stream) {
    const float* x      = (const float*)d_in[0];
    const float* st     = (const float*)d_in[1];
    const float* adj    = (const float*)d_in[2];
    const float* P      = (const float*)d_in[3];
    const float* H1_0   = (const float*)d_in[4];
    const float* H2_0   = (const float*)d_in[6];
    const float* W_encD = (const float*)d_in[8];
    const float* b_encD = (const float*)d_in[9];
    const float* W_encAD= (const float*)d_in[10];
    const float* b_encAD= (const float*)d_in[11];
    const float* W_dec  = (const float*)d_in[12];
    const float* b_dec  = (const float*)d_in[13];
    const float* W_fc   = (const float*)d_in[14];
    const float* b_fc   = (const float*)d_in[15];
    const float* W_aggH = (const float*)d_in[16];
    const float* b_aggH = (const float*)d_in[17];
    const float* W_camH = (const float*)d_in[20];
    const float* b_camH = (const float*)d_in[21];
    const float* wL     = (const float*)d_in[24];
    const float* bL     = (const float*)d_in[25];
    const float* wH     = (const float*)d_in[26];
    const float* bH     = (const float*)d_in[27];

    float* ws   = (float*)d_ws;
    float* G    = ws + OFF_G;
    float* rs   = ws + OFF_RS;
    float* cs   = rs + NN;
    float* rv   = ws + OFF_RV;
    float* Weff = ws + OFF_WEFF;
    f16*   Wt   = (f16*)(ws + OFF_WT);
    f16*   G16  = (f16*)(ws + OFF_G16);
    float* Mw   = ws + OFF_M;
    float* tv   = ws + OFF_TV;
    f16*   xs   = (f16*)(ws + OFF_XS);
    f16*   Dbuf = (f16*)(ws + OFF_DBUF);
    float* ZR   = ws + OFF_ZR;
    float* G2   = ZR;                 // alias: G2 only used in prep
    float* Henc = ws + OFF_HENC;
    float* Hdec = ws + OFF_HDEC;
    float* ys   = ws + OFF_YS;

    // ---- prep ----
    k_sums<<<NN, 64, 0, stream>>>(adj, rs, cs);
    k_buildG<<<(NN*NN + 255)/256, 256, 0, stream>>>(adj, P, rs, cs, G);
    k_gg<<<dim3(11,11,2), 256, 0, stream>>>(G, G2);
    k_g16<<<(4*G16_MAT + 255)/256, 256, 0, stream>>>(G, G2, G16);
    k_rowsum<<<650, 64, 0, stream>>>(G, G2, rv);
    k_weff<<<255, 256, 0, stream>>>(W_encD,  b_encD,  Weff);
    k_weff<<<255, 256, 0, stream>>>(W_encAD, b_encAD, Weff + WSET);
    k_weff<<<255, 256, 0, stream>>>(W_dec,   b_dec,   Weff + 2*WSET);
    k_wt<<<(192*352 + 255)/256, 256, 0, stream>>>(Weff, Wt);
    k_wt<<<(192*352 + 255)/256, 256, 0, stream>>>(Weff + WSET, Wt + WT_SET);
    k_wt<<<(192*352 + 255)/256, 256, 0, stream>>>(Weff + 2*WSET, Wt + 2*WT_SET);
    k_M<<<(325*192 + 255)/256, 256, 0, stream>>>(Weff, rv, Mw);
    k_M<<<(325*192 + 255)/256, 256, 0, stream>>>(Weff + WSET, rv, Mw + M_SET);
    k_M<<<(325*192 + 255)/256, 256, 0, stream>>>(Weff + 2*WSET, rv, Mw + 2*M_SET);
    k_tv<<<3, 256, 0, stream>>>(st, tv);
    k_xs16<<<(2*TENC*NB*4 + 255)/256, 256, 0, stream>>>(x, xs);
    k_initH<<<(2*NB*64 + 255)/256, 256, 0, stream>>>(H1_0, H2_0, Henc);
    k_init0<<<(2*NB*CCOMB + 255)/256, 256, 0, stream>>>(xs, H1_0, H2_0, Dbuf);

    // ---- encoders (E=2): per step: diff, proj0(z->ZR, rH->plane0), diff, proj1(H) ----
    for (int t = 0; t < TENC; t++) {
        const f16* xn0 = (t < TENC-1) ? (xs + (size_t)(t+1)*NB*4) : nullptr;
        const f16* xn1 = (t < TENC-1) ? (xs + (size_t)(TENC + t+1)*NB*4) : nullptr;
        k_diff16<<<dim3(34,6,8), 256, 0, stream>>>(G16, Dbuf);
        k_proj16<0><<<dim3(163,2), 256, 0, stream>>>(Dbuf, Wt, WT_SET, Weff, WSET,
                                                     Mw, M_SET, tv + (size_t)t*32,
                                                     ZR, Henc, nullptr, nullptr);
        k_diff16<<<dim3(34,6,8), 256, 0, stream>>>(G16, Dbuf);
        k_proj16<1><<<dim3(163,2), 256, 0, stream>>>(Dbuf, Wt, WT_SET, Weff, WSET,
                                                     Mw, M_SET, tv + (size_t)t*32,
                                                     ZR, Henc, xn0, xn1);
    }

    // ---- fuse + decoder plane0 init ----
    k_fuse16<<<163, 256, 0, stream>>>(Henc, Henc + (size_t)NB*64,
                                      wL, bL, wH, bH, W_camH, b_camH, W_aggH, b_aggH,
                                      Hdec, Dbuf);

    // ---- decoder (E=1, weight set 2) ----
    for (int t = 0; t < TDEC; t++) {
        const float* tvt = tv + (size_t)(6 + t)*32;
        k_diff16<<<dim3(34,6,4), 256, 0, stream>>>(G16, Dbuf);
        k_proj16<0><<<dim3(163,1), 256, 0, stream>>>(Dbuf, Wt + 2*WT_SET, 0,
                                                     Weff + 2*WSET, 0,
                                                     Mw + 2*M_SET, 0, tvt,
                                                     ZR, Hdec, nullptr, nullptr);
        k_diff16<<<dim3(34,6,4), 256, 0, stream>>>(G16, Dbuf);
        k_proj16<1><<<dim3(163,1), 256, 0, stream>>>(Dbuf, Wt + 2*WT_SET, 0,
                                                     Weff + 2*WSET, 0,
                                                     Mw + 2*M_SET, 0, tvt,
                                                     ZR, Hdec, nullptr, nullptr);
        k_fc<<<(NB*3 + 255)/256, 256, 0, stream>>>(Hdec, W_fc, b_fc,
                                                   ys + (size_t)t*NB*3, Dbuf);
    }

    k_out<<<(BB*3*NN*12 + 255)/256, 256, 0, stream>>>(ys, (float*)d_out);
}